// Round 7
// baseline (243.392 us; speedup 1.0000x reference)
//
#include <hip/hip_runtime.h>

// MHA: B=4 T=2048 C=1024 H=16 HD=64, causal, fp32 in/out, bf16 MFMA internally.
// Pipeline: prep(cast+transposes, fused) -> GEMM1(QKV, V transposed, Q pre-scaled)
//           -> flash-attn -> GEMM2.
// R13 = R12 (gemm 3-buffer counted-vmcnt mainloops, verified 68.6us gemm1)
// with attn REWRITTEN to the m214-style structure. Makespan accounting showed
// total - gemm1 ~= 168us in EVERY round -> attn ~= 110us (~280 TF) dominates.
// Old attn: P = exp2(QK^T) went through LDS via 32 scalar ds_writes + reads
// per wave-tile (~96 pack-VALU + 36 LDS ops). New attn:
//  - swapped QK^T: compute S^T = K.Q^T with mfma_32x32x16 -> each lane owns
//    ONE q-row's scores in registers (C/D layout: col=lane&31 = q-row).
//  - P stays in registers: exp2 -> v_cvt_pk_bf16_f32 pairs -> one
//    shfl_xor(32) exchange rebuilds the PV A-fragments (k = hi*8+j order).
//  - PV: mfma_32x32x16(P, V) reading V^T straight from the same swizzled
//    LDS layout as before. l-sum = 1 scalar/lane + 1 shfl_xor(32) at end.
// K/V staging, double-buffer, causal skip, grid, bare-exp2 all unchanged.
// LDS 48K -> 32K; per-tile LDS ops 36 -> 16; MFMA 32x16x16-class -> 16x32x32.

typedef unsigned short u16;
typedef short short8_t __attribute__((ext_vector_type(8)));
typedef float f32x4 __attribute__((ext_vector_type(4)));
typedef float f32x16 __attribute__((ext_vector_type(16)));
typedef unsigned int u32x4 __attribute__((ext_vector_type(4)));

#define B_ 4
#define T_ 2048
#define C_ 1024
#define H_ 16
#define HD_ 64
// 0.125 * log2(e): folded into Q at GEMM1 epilogue so attn uses bare exp2.
#define QSCALE 0.18033688011112042f

__device__ __forceinline__ u16 f32_to_bf16(float f) {
  unsigned int u = __float_as_uint(f);
  u += 0x7fffu + ((u >> 16) & 1u);  // RNE
  return (u16)(u >> 16);
}

__device__ __forceinline__ void async_copy16(const void* g, void* l) {
  __builtin_amdgcn_global_load_lds((const __attribute__((address_space(1))) void*)g,
                                   (__attribute__((address_space(3))) void*)l, 16, 0, 0);
}

__device__ __forceinline__ void wave_barrier() { asm volatile("s_barrier" ::: "memory"); }
template <int N>
__device__ __forceinline__ void wait_vmcnt() {
  asm volatile("s_waitcnt vmcnt(%0)" ::"i"(N) : "memory");
}

__device__ __forceinline__ unsigned int cvt_pk_bf16(float lo, float hi) {
  unsigned int r;
  asm("v_cvt_pk_bf16_f32 %0, %1, %2" : "=v"(r) : "v"(lo), "v"(hi));
  return r;
}

// ---------------- fused prep: cast x + transpose both weights ----------------
__device__ __forceinline__ void transpose_tile(const float* __restrict__ in,
                                               u16* __restrict__ out, int K, int N, int bx, int by,
                                               float (*tile)[33], int tid) {
  int nb = bx * 32, kb = by * 32;
  int c = tid & 31, r0 = tid >> 5;
#pragma unroll
  for (int rr = 0; rr < 4; ++rr) {
    int r = r0 + rr * 8;
    tile[r][c] = in[(size_t)(kb + r) * N + nb + c];
  }
  __syncthreads();
#pragma unroll
  for (int rr = 0; rr < 4; ++rr) {
    int r = r0 + rr * 8;
    out[(size_t)(nb + r) * K + kb + c] = f32_to_bf16(tile[c][r]);
  }
}

__global__ void prep_kernel(const float* __restrict__ x, u16* __restrict__ Xb,
                            const float* __restrict__ Wqkv, u16* __restrict__ WqkvT,
                            const float* __restrict__ Wproj, u16* __restrict__ WprojT) {
  __shared__ float tile[32][33];
  int id = blockIdx.x;
  int tid = threadIdx.x;
  if (id < 8192) {
    int i = id * 256 + tid;
    float4 v = ((const float4*)x)[i];
    unsigned int a = (unsigned int)f32_to_bf16(v.x) | ((unsigned int)f32_to_bf16(v.y) << 16);
    unsigned int b = (unsigned int)f32_to_bf16(v.z) | ((unsigned int)f32_to_bf16(v.w) << 16);
    ((uint2*)Xb)[i] = make_uint2(a, b);
  } else if (id < 11264) {
    int t = id - 8192;
    transpose_tile(Wqkv, WqkvT, C_, 3 * C_, t % 96, t / 96, tile, tid);
  } else {
    int t = id - 11264;
    transpose_tile(Wproj, WprojT, C_, C_, t % 32, t / 32, tile, tid);
  }
}

// ------------- shared 128x128 GEMM mainloop (3-buffer counted-vmcnt) -------------
__device__ __forceinline__ void stage_tile(const u16* __restrict__ A, const u16* __restrict__ Bt,
                                           int K, int m0, int n0, int k0, char* buf, int tid) {
#pragma unroll
  for (int it = 0; it < 2; ++it) {
    int j = it * 256 + tid;
    int row = j >> 2;
    int ch = ((j & 3) ^ (row >> 1)) & 3;
    async_copy16(A + (size_t)(m0 + row) * K + k0 + ch * 8, buf + j * 16);
    async_copy16(Bt + (size_t)(n0 + row) * K + k0 + ch * 8, buf + 8192 + j * 16);
  }
}

__device__ __forceinline__ void gemm_mainloop(const u16* __restrict__ A, const u16* __restrict__ Bt,
                                              int K, int m0, int n0, char* smem,
                                              f32x4 (&acc)[4][4]) {
  int tid = threadIdx.x;
  int lane = tid & 63, wave = tid >> 6;
  int quad = lane >> 4, l15 = lane & 15;
  int waveM = wave >> 1, waveN = wave & 1;
  int nIter = K >> 5;  // 32
  stage_tile(A, Bt, K, m0, n0, 0, smem, tid);
  stage_tile(A, Bt, K, m0, n0, 32, smem + 16384, tid);
  int cur = 0;
  for (int ki = 0; ki < nIter; ++ki) {
    int nxt2 = cur + 2;
    if (nxt2 >= 3) nxt2 -= 3;
    if (ki + 2 < nIter) {
      stage_tile(A, Bt, K, m0, n0, (ki + 2) << 5, smem + nxt2 * 16384, tid);
      wait_vmcnt<8>();  // retire tile ki's 4 loads
    } else if (ki + 2 == nIter) {
      wait_vmcnt<4>();
    } else {
      wait_vmcnt<0>();
    }
    wave_barrier();  // all waves' tile-ki staging writes visible
    char* bufc = smem + cur * 16384;
    short8_t af[4], bfr[4];
#pragma unroll
    for (int mt = 0; mt < 4; ++mt) {
      int row = waveM * 64 + mt * 16 + l15;
      af[mt] = *(const short8_t*)(bufc + row * 64 + (((quad ^ (row >> 1)) & 3) << 4));
    }
#pragma unroll
    for (int nt = 0; nt < 4; ++nt) {
      int row = waveN * 64 + nt * 16 + l15;
      bfr[nt] = *(const short8_t*)(bufc + 8192 + row * 64 + (((quad ^ (row >> 1)) & 3) << 4));
    }
    __builtin_amdgcn_s_setprio(1);
#pragma unroll
    for (int mt = 0; mt < 4; ++mt)
#pragma unroll
      for (int nt = 0; nt < 4; ++nt)
        acc[mt][nt] = __builtin_amdgcn_mfma_f32_16x16x32_bf16(af[mt], bfr[nt], acc[mt][nt], 0, 0, 0);
    __builtin_amdgcn_s_setprio(0);
    wave_barrier();  // protects buf[cur] until all waves read it
    cur = cur + 1;
    if (cur == 3) cur = 0;
  }
}

// -------- GEMM1: X[8192x1024] @ WqkvT -> Q,K [B,H,T,HD]; V [B,H,HD,T] --------
__global__ __launch_bounds__(256, 3) void gemm1_kernel(const u16* __restrict__ A,
                                                       const u16* __restrict__ Bt,
                                                       const float* __restrict__ bias,
                                                       u16* __restrict__ Qo, u16* __restrict__ Ko,
                                                       u16* __restrict__ Vo) {
  __shared__ __align__(128) char smem[49152];
  f32x4 acc[4][4];
#pragma unroll
  for (int mt = 0; mt < 4; ++mt)
#pragma unroll
    for (int nt = 0; nt < 4; ++nt) acc[mt][nt] = (f32x4){0.f, 0.f, 0.f, 0.f};
  int m0 = blockIdx.y * 128, n0 = blockIdx.x * 128;
  gemm_mainloop(A, Bt, C_, m0, n0, smem, acc);

  int lane = threadIdx.x & 63, wave = threadIdx.x >> 6;
  int quad = lane >> 4, l15 = lane & 15;
  int waveM = wave >> 1, waveN = wave & 1;

  if (n0 < 2048) {
    // ---- Q/K: direct scalar stores; Q pre-scaled by QSCALE ----
#pragma unroll
    for (int nt = 0; nt < 4; ++nt) {
      int n = n0 + waveN * 64 + nt * 16;
      int which = n >> 10;
      int rem = n & 1023;
      int head = rem >> 6;
      int d = (rem & 63) + l15;
      float bv = bias[n + l15];
      float sc = (which == 0) ? QSCALE : 1.0f;
      u16* dst = (which == 0) ? Qo : Ko;
#pragma unroll
      for (int mt = 0; mt < 4; ++mt) {
#pragma unroll
        for (int r = 0; r < 4; ++r) {
          int token = m0 + waveM * 64 + mt * 16 + quad * 4 + r;
          int b = token >> 11, t = token & 2047;
          dst[(((size_t)(b * H_ + head)) * T_ + t) * HD_ + d] =
              f32_to_bf16((acc[mt][nt][r] + bv) * sc);
        }
      }
    }
  } else {
    // ---- V: transpose wave's 64x64 quadrant through LDS, store V^T rows ----
    __syncthreads();  // staging LDS dead
    char* W = smem + wave * 8192;  // [n-local 64 rows][128B], 16B chunks XOR-swizzled
#pragma unroll
    for (int nt = 0; nt < 4; ++nt) {
      int nl = nt * 16 + l15;  // wave-local col
      float bv = bias[n0 + waveN * 64 + nl];
#pragma unroll
      for (int mt = 0; mt < 4; ++mt) {
        int g = mt * 4 + quad;               // 8B granule index (4 bf16)
        int pc = ((g >> 1) ^ (nl & 7)) & 7;  // swizzled 16B chunk
        uint2 pv;
        pv.x = (unsigned int)f32_to_bf16(acc[mt][nt][0] + bv) |
               ((unsigned int)f32_to_bf16(acc[mt][nt][1] + bv) << 16);
        pv.y = (unsigned int)f32_to_bf16(acc[mt][nt][2] + bv) |
               ((unsigned int)f32_to_bf16(acc[mt][nt][3] + bv) << 16);
        *(uint2*)(W + nl * 128 + pc * 16 + (g & 1) * 8) = pv;
      }
    }
    int b = m0 >> 11;
#pragma unroll
    for (int i = 0; i < 8; ++i) {
      int jj = i * 64 + lane;
      int nl = jj >> 3;  // d-local row
      int c = jj & 7;    // logical 16B chunk = tokens c*8..c*8+7
      int pc = c ^ (nl & 7);
      uint4 v = *(const uint4*)(W + nl * 128 + pc * 16);
      int rem = (n0 - 2048) + waveN * 64 + nl;
      int head = rem >> 6, dd = rem & 63;
      int t0 = (m0 & 2047) + waveM * 64 + c * 8;
      *(uint4*)(Vo + ((size_t)(b * H_ + head) * HD_ + dd) * T_ + t0) = v;
    }
  }
}

// -------- GEMM2: Y[8192x1024] @ WprojT + bproj -> out fp32 --------
__global__ __launch_bounds__(256, 3) void gemm2_kernel(const u16* __restrict__ A,
                                                       const u16* __restrict__ Bt,
                                                       const float* __restrict__ bias,
                                                       float* __restrict__ out) {
  __shared__ __align__(128) char smem[49152];
  f32x4 acc[4][4];
#pragma unroll
  for (int mt = 0; mt < 4; ++mt)
#pragma unroll
    for (int nt = 0; nt < 4; ++nt) acc[mt][nt] = (f32x4){0.f, 0.f, 0.f, 0.f};
  int m0 = blockIdx.y * 128, n0 = blockIdx.x * 128;
  gemm_mainloop(A, Bt, C_, m0, n0, smem, acc);

  int lane = threadIdx.x & 63, wave = threadIdx.x >> 6;
  int quad = lane >> 4, l15 = lane & 15;
  int waveM = wave >> 1, waveN = wave & 1;
#pragma unroll
  for (int nt = 0; nt < 4; ++nt) {
    int col = n0 + waveN * 64 + nt * 16 + l15;
    float bv = bias[col];
#pragma unroll
    for (int mt = 0; mt < 4; ++mt) {
#pragma unroll
      for (int r = 0; r < 4; ++r) {
        int token = m0 + waveM * 64 + mt * 16 + quad * 4 + r;
        out[(size_t)token * C_ + col] = acc[mt][nt][r] + bv;
      }
    }
  }
}

// ======== flash attention: swapped-QK^T 32x32 MFMA, P fully in registers ========
// Q,K in [B,H,T,HD] (Q pre-scaled); V in [B,H,HD,T]; Y out [B,T,C] bf16.
// 4 waves x 32 q-rows (Q-tile 128), KVBLK=64, K/V double-buffered in LDS
// (same layouts/swizzle/staging as before). Per tile:
//   S^T = K.Q^T via 8x mfma_32x32x16 (A=K-frag from LDS, B=Q-frag in regs);
//   lane owns q-row (lane&31); k-pos of reg r = kb*32+(r&3)+8*(r>>2)+4*hi.
//   P = exp2(S^T) in regs; causal mask per-element on the wave's diag tile.
//   PV A-frags rebuilt in-register: cvt_pk bf16 pairs + shfl_xor(32) swaps
//   the hi/lo half k-quads (lane L <-> L^32). O += P.V via 8x mfma_32x32x16
//   (B=V-frag from swizzled V^T LDS). l = 1 scalar/lane, reduced at epilogue.
__device__ __forceinline__ void stage_kv(const u16* __restrict__ Kb, const u16* __restrict__ Vb,
                                         int kt, char* Ksb, char* Vsb, int tid) {
#pragma unroll
  for (int it = 0; it < 2; ++it) {
    int j = it * 256 + tid;
    int row = j >> 3;
    int ch = (j & 7) ^ (row & 7);
    async_copy16(Kb + (size_t)(kt * 64 + row) * HD_ + ch * 8, Ksb + j * 16);
    async_copy16(Vb + (size_t)row * T_ + kt * 64 + ch * 8, Vsb + j * 16);
  }
}

// exp2 (+ optional causal mask) over one 32-k block; returns partial row-sum.
__device__ __forceinline__ float softmax_block(f32x16& s, int kbase_g, bool diag, int qrow_g,
                                               int hi) {
  float lsum = 0.f;
#pragma unroll
  for (int r = 0; r < 16; ++r) {
    float p = __builtin_amdgcn_exp2f(s[r]);
    if (diag) {
      int kpos = kbase_g + (r & 3) + 8 * (r >> 2) + 4 * hi;
      if (kpos > qrow_g) p = 0.f;
    }
    s[r] = p;
    lsum += p;
  }
  return lsum;
}

// Pack one 32-k P block (16 f32, k = (r&3)+8*(r>>2)+4*hi) into two PV A-frags
// (k = hi*8+j order) via bf16 pair-pack + lane<->lane^32 exchange.
__device__ __forceinline__ void pack_pfrags(const f32x16& s, int hi, short8_t& f0, short8_t& f1) {
  unsigned int pk[8], qk[8];
#pragma unroll
  for (int j = 0; j < 8; ++j) pk[j] = cvt_pk_bf16(s[2 * j], s[2 * j + 1]);
#pragma unroll
  for (int j = 0; j < 8; ++j) qk[j] = (unsigned int)__shfl_xor((int)pk[j], 32);
  u32x4 w0, w1;
  if (hi == 0) {
    // k 0-7: own (0,1),(2,3) + partner (4,5),(6,7); k 16-23 likewise from j4,j5
    w0 = (u32x4){pk[0], pk[1], qk[0], qk[1]};
    w1 = (u32x4){pk[4], pk[5], qk[4], qk[5]};
  } else {
    // k 8-15: partner (8,9),(10,11) + own (12,13),(14,15); k 24-31 from j6,j7
    w0 = (u32x4){qk[2], qk[3], pk[2], pk[3]};
    w1 = (u32x4){qk[6], qk[7], pk[6], pk[7]};
  }
  f0 = __builtin_bit_cast(short8_t, w0);
  f1 = __builtin_bit_cast(short8_t, w1);
}

#define MFMA32(a, b, c) __builtin_amdgcn_mfma_f32_32x32x16_bf16(a, b, c, 0, 0, 0)

__global__ __launch_bounds__(256, 3) void attn_kernel(const u16* __restrict__ Qg,
                                                      const u16* __restrict__ Kg,
                                                      const u16* __restrict__ Vg,
                                                      u16* __restrict__ Yg) {
  __shared__ __align__(128) char smem[32768];
  int tid = threadIdx.x;
  int wave = tid >> 6, lane = tid & 63;
  int l31 = lane & 31, hi = lane >> 5;
  int bh = blockIdx.x;
  int qt = 15 - blockIdx.y;  // heaviest blocks dispatch first (x-major)
  int b = bh >> 4, h = bh & 15;
  const u16* Kb = Kg + (size_t)bh * T_ * HD_;
  const u16* Vb = Vg + (size_t)bh * HD_ * T_;
  int qrow = qt * 128 + wave * 32 + l31;  // this lane's q-row (global)

  // ---- Q frags (B-operand: col=q=l31, k(d) = f*16 + hi*8 + j), from global ----
  short8_t qf[4];
#pragma unroll
  for (int f = 0; f < 4; ++f)
    qf[f] = *(const short8_t*)(Qg + ((size_t)bh * T_ + qrow) * HD_ + f * 16 + hi * 8);

  stage_kv(Kb, Vb, 0, smem, smem + 16384, tid);  // prefetch tile 0

  float l_lane = 0.f;
  f32x16 o0, o1;
#pragma unroll
  for (int i = 0; i < 16; ++i) {
    o0[i] = 0.f;
    o1[i] = 0.f;
  }

  int ktmax_blk = 2 * qt + 1;
  int ktmax_wave = 2 * qt + (wave >> 1);  // last tile this wave's rows need
  for (int kt = 0; kt <= ktmax_blk; ++kt) {
    int cur = kt & 1;
    char* Ksc = smem + cur * 8192;
    char* Vtc = smem + 16384 + cur * 8192;
    __syncthreads();  // publish buf[cur]; all waves done reading buf[cur^1]
    if (kt < ktmax_blk)
      stage_kv(Kb, Vb, kt + 1, smem + (cur ^ 1) * 8192, smem + 16384 + (cur ^ 1) * 8192, tid);
    if (kt > ktmax_wave) continue;  // causally irrelevant; rejoin at barrier

    // ---- S^T = K.Q^T : A-frag = K rows (kpos), k(d)-chunks; acc per kb ----
    f32x16 s0, s1;
#pragma unroll
    for (int i = 0; i < 16; ++i) {
      s0[i] = 0.f;
      s1[i] = 0.f;
    }
    int swz7 = l31 & 7;
#pragma unroll
    for (int f = 0; f < 4; ++f) {
      int pc = (((f * 2 + hi) ^ swz7) & 7) << 4;
      short8_t kf0 = *(const short8_t*)(Ksc + l31 * 128 + pc);
      short8_t kf1 = *(const short8_t*)(Ksc + (32 + l31) * 128 + pc);
      s0 = MFMA32(kf0, qf[f], s0);
      s1 = MFMA32(kf1, qf[f], s1);
    }

    // ---- P = exp2(S^T) in regs (+ causal mask on the wave's diagonal tile) ----
    bool diag = (kt == ktmax_wave);
    l_lane += softmax_block(s0, kt * 64, diag, qrow, hi);
    l_lane += softmax_block(s1, kt * 64 + 32, diag, qrow, hi);

    // ---- rebuild PV A-frags in-register ----
    short8_t pf0, pf1, pf2, pf3;
    pack_pfrags(s0, hi, pf0, pf1);
    pack_pfrags(s1, hi, pf2, pf3);

    // ---- O += P.V : B-frag = V^T rows (d), k(t)-chunks ----
#pragma unroll
    for (int f = 0; f < 4; ++f) {
      int pc = (((f * 2 + hi) ^ swz7) & 7) << 4;
      short8_t va = *(const short8_t*)(Vtc + l31 * 128 + pc);
      short8_t vb = *(const short8_t*)(Vtc + (32 + l31) * 128 + pc);
      short8_t pf = (f == 0) ? pf0 : (f == 1) ? pf1 : (f == 2) ? pf2 : pf3;
      o0 = MFMA32(pf, va, o0);
      o1 = MFMA32(pf, vb, o1);
    }
  }

  // ---- epilogue: full row-sum, divide, store (lane owns d-col l31/+32) ----
  float lc = l_lane + __shfl_xor(l_lane, 32);
#pragma unroll
  for (int r = 0; r < 16; ++r) {
    int q_r = (r & 3) + 8 * (r >> 2) + 4 * hi;  // wave-local q-row of this reg
    float inv = 1.0f / __shfl(lc, q_r);
    int t = qt * 128 + wave * 32 + q_r;
    size_t base = ((size_t)(b * T_ + t)) * C_ + h * HD_;
    Yg[base + l31] = f32_to_bf16(o0[r] * inv);
    Yg[base + 32 + l31] = f32_to_bf16(o1[r] * inv);
  }
}

extern "C" void kernel_launch(void* const* d_in, const int* in_sizes, int n_in,
                              void* d_out, int out_size, void* d_ws, size_t ws_size,
                              hipStream_t stream) {
  (void)in_sizes; (void)n_in; (void)out_size; (void)ws_size;
  const float* x = (const float*)d_in[0];
  const float* Wqkv = (const float*)d_in[1];
  const float* bqkv = (const float*)d_in[2];
  const float* Wproj = (const float*)d_in[3];
  const float* bproj = (const float*)d_in[4];
  float* out = (float*)d_out;
  char* ws = (char*)d_ws;

  // workspace layout (75.5 MB total):
  u16* Xb = (u16*)ws;                             // 16.78 MB, reused as Y after GEMM1
  u16* WqkvT = (u16*)(ws + 16777216);             //  6.29 MB  [3072][1024]
  u16* WprojT = (u16*)(ws + 16777216 + 6291456);  //  2.10 MB  [1024][1024]
  u16* Q = (u16*)(ws + 25165824);                 // 16.78 MB  [B,H,T,HD] (pre-scaled)
  u16* K = Q + 8388608;                           // 16.78 MB  [B,H,T,HD]
  u16* V = K + 8388608;                           // 16.78 MB  [B,H,HD,T]
  u16* Y = Xb;  // alias: Xb dead after GEMM1

  prep_kernel<<<12288, 256, 0, stream>>>(x, Xb, Wqkv, WqkvT, Wproj, WprojT);
  gemm1_kernel<<<dim3(24, 64), 256, 0, stream>>>(Xb, WqkvT, bqkv, Q, K, V);
  attn_kernel<<<dim3(64, 16), 256, 0, stream>>>(Q, K, V, Y);
  gemm2_kernel<<<dim3(8, 64), 256, 0, stream>>>(Y, WprojT, bproj, out);
}